// Round 8
// baseline (163.618 us; speedup 1.0000x reference)
//
#include <hip/hip_runtime.h>

namespace {

typedef __attribute__((ext_vector_type(2))) float f32x2;
typedef __attribute__((ext_vector_type(4))) float f32x4;

constexpr int Hd = 512, Wd = 512;
constexpr int TH = 32;             // output rows per block. TH=52 (round 7)
                                   // regressed: NCH=13 fully-unrolled periods
                                   // overflow the 32KB I$ (VALUBusy 43->36%).
constexpr int R  = 2;              // rows per LDS phase (round-8: was 4).
                                   // Halves LDS to 33.5KB -> 4 blocks/CU
                                   // capacity, all 768 blocks co-resident.
constexpr int NCH = TH / R;        // 16 chunks
constexpr int RAD = 5, WS = 11;
// Pair-interleaved transposed staging (round-8 re-derivation of the round-3
// idea for R=2): staged element e (column e-5) at slot s(e)=(e&1)*SPAN+(e>>1).
//   reads:  thread (hr,hu) needs elems 2hu+t, t=0..11 -> slot = hu + (t&1)*SPAN
//           + (t>>1): ONE base, lane stride 16B (dense 1024B/wave), 12
//           compile-time immediates. Conflict-free.
//   writes: thread c writes e=c+5 -> two dense 512B segments (even/odd c),
//           2-way at worst (free per m136).
constexpr int SPAN = 262;          // ceil(522/2)
constexpr int RSTR = 2 * SPAN;     // 524 f32x4 elements per staged row
constexpr float C1c = 1e-4f;       // (0.01*1.0)^2
constexpr float C2c = 9e-4f;       // (0.03*1.0)^2

__device__ __forceinline__ float rcp_fast(float x) { return __builtin_amdgcn_rcpf(x); }
__device__ __forceinline__ float sgpr_f(float x) {
    return __int_as_float(__builtin_amdgcn_readfirstlane(__float_as_int(x)));
}
__device__ __forceinline__ constexpr int sw(int e) { return (e & 1) * SPAN + (e >> 1); }

// Round-6 schedule (kept): double-buffered ping-pong, ONE barrier per chunk.
// Period = {barrier; prefetch ch+2; H(ch) from hb[ch&1]; V(ch+1) into
// hb[(ch+1)&1]}. V(ch+1)'s writes are separated from H(ch-1)'s reads of the
// same buffer by barrier(ch); in-period H and V use different buffers.
// Round-8 addition: at 33.5KB LDS, 3 blocks/CU are resident (24 waves), so
// each block's barrier drain is covered by the other two blocks' waves.

#define VPHASE(CH, PA, PB, BUF)                                         \
    _Pragma("unroll")                                                   \
    for (int i = 0; i < R; ++i) {                                       \
        const int o = (CH) * R + i;                                     \
        const int j = o + 2 * RAD;                                      \
        const float a = (PA)[i];                                        \
        const float b = (PB)[i];                                        \
        f32x2 sd; sd.x = a + b; sd.y = a - b;                           \
        const f32x2 qq = sd * sd;                                       \
        _Pragma("unroll")                                               \
        for (int k = 0; k < WS; ++k) {                                  \
            const int slot = (j - k) % WS;   /* static after unroll */  \
            f32x2 w2; w2.x = g[k]; w2.y = g[k];                         \
            aM[slot] = __builtin_elementwise_fma(w2, sd, aM[slot]);     \
            aQ[slot] = __builtin_elementwise_fma(w2, qq, aQ[slot]);     \
        }                                                               \
        const int es = o % WS;                                          \
        f32x4 e;                                                        \
        e.x = aM[es].x; e.y = aM[es].y;                                 \
        e.z = aQ[es].x; e.w = aQ[es].y;                                 \
        (BUF)[i * RSTR + wmain] = e;                                    \
        if (whalo >= 0) (BUF)[i * RSTR + whalo] = e;                    \
        aM[es].x = 0.f; aM[es].y = 0.f;                                 \
        aQ[es].x = 0.f; aQ[es].y = 0.f;                                 \
    }

#define PREFETCH(CHUNK, PA, PB)                                         \
    _Pragma("unroll")                                                   \
    for (int i = 0; i < R; ++i) {                                       \
        int gr = row0 + RAD + (CHUNK) * R + i;                          \
        gr = (gr >= Hd) ? (2 * Hd - 2 - gr) : gr;                       \
        const long off = pbase + (long)gr * Wd + c;                     \
        (PA)[i] = img1[off];                                            \
        (PB)[i] = img2[off];                                            \
    }

// 33.5 KB LDS; (512,8) caps VGPR at 64 so 4 blocks/CU are schedulable.
__global__ __launch_bounds__(512, 8) void ssim_map_kernel(
    const float* __restrict__ img1,
    const float* __restrict__ img2,
    const float* __restrict__ kern,
    float* __restrict__ out)
{
    // packed {mS, mD, QS, QD} per column, R rows, pair-transposed, x2 buffers
    __shared__ __align__(16) f32x4 hb[2][R * RSTR];   // 33.5 KB

    const int tid  = threadIdx.x;
    const int c    = tid;                       // owned column
    const int row0 = blockIdx.x * TH;
    const long pbase = (long)blockIdx.y * (long)(Hd * Wd);

    // ---- 1D gaussian (uniform -> SGPRs): g[j] = k[5][j]/sum ----
    float g[WS];
    {
        float s = 0.f;
#pragma unroll
        for (int j = 0; j < WS; ++j) s += kern[RAD * WS + j];
        const float inv = 1.0f / s;
#pragma unroll
        for (int j = 0; j < WS; ++j) g[j] = sgpr_f(kern[RAD * WS + j] * inv);
    }

    // ---- precomputed transposed write slots (loop-invariant) ----
    const int wmain = sw(c + RAD);              // staged element c+5
    int whalo = -1;
    if (c >= 1 && c <= RAD) whalo = sw(RAD - c);                       // left reflect
    else if (c >= Wd - 1 - RAD && c <= Wd - 2) whalo = sw(RAD + 1022 - c); // right

    // ---- ring accumulators, slot(out_row o) = o % 11 ----
    f32x2 aM[WS];   // {conv(S), conv(D)}
    f32x2 aQ[WS];   // {conv(S^2), conv(D^2)}
#pragma unroll
    for (int i = 0; i < WS; ++i) {
        aM[i].x = 0.f; aM[i].y = 0.f;
        aQ[i].x = 0.f; aQ[i].y = 0.f;
    }

    // ---- fill: input idx j=0..9 (rows row0-5+j), taps k<=j ----
#pragma unroll
    for (int j = 0; j < 2 * RAD; ++j) {
        int gr = row0 - RAD + j;                // uniform reflect -> SALU
        gr = (gr < 0) ? -gr : gr;
        gr = (gr >= Hd) ? (2 * Hd - 2 - gr) : gr;
        const long off = pbase + (long)gr * Wd + c;
        const float a = img1[off];
        const float b = img2[off];
        f32x2 sd; sd.x = a + b; sd.y = a - b;
        const f32x2 qq = sd * sd;               // v_pk_mul_f32
#pragma unroll
        for (int k = 0; k < WS; ++k) {
            if (k <= j) {
                const int slot = (j - k) % WS;  // static after unroll
                f32x2 w2; w2.x = g[k]; w2.y = g[k];
                aM[slot] = __builtin_elementwise_fma(w2, sd, aM[slot]);
                aQ[slot] = __builtin_elementwise_fma(w2, qq, aQ[slot]);
            }
        }
    }

    // ---- T14 prefetch registers, double set: V(k) consumes (k even ? A : B)
    float plaA[R], plbA[R], plaB[R], plbB[R];
    PREFETCH(0, plaA, plbA)                     // chunk 0
    PREFETCH(1, plaB, plbB)                     // chunk 1

    // ---- V(0) -> hb[0] (no barrier needed before first use) ----
    VPHASE(0, plaA, plbA, (&hb[0][0]))

    const int hr = tid >> 8;      // horizontal: row in chunk (0..1)
    const int hu = tid & 255;     // horizontal: out cols 2hu, 2hu+1

#pragma unroll
    for (int ch = 0; ch < NCH; ++ch) {
        __syncthreads();          // hb[ch&1] complete; prior readers of
                                  // hb[(ch+1)&1] (H(ch-1)) are done

        // ---- issue chunk ch+2 loads into the set V(ch) already consumed ----
        if (ch + 2 < NCH) {
            if ((ch & 1) == 0) { PREFETCH(ch + 2, plaA, plbA) }
            else               { PREFETCH(ch + 2, plaB, plbB) }
        }

        // ---- H(ch): 2 cols x 1 row per thread, reads hb[ch&1] ----
        f32x2 hm[2], hq[2];
#pragma unroll
        for (int j = 0; j < 2; ++j) {
            hm[j].x = 0.f; hm[j].y = 0.f;
            hq[j].x = 0.f; hq[j].y = 0.f;
        }
        // base lane-stride = 1 element (16B): dense wave reads, offsets imm
        const f32x4* base = &hb[ch & 1][hr * RSTR + hu];
#pragma unroll
        for (int t = 0; t < 12; ++t) {          // staged elem 2hu+t (col 2hu+t-5)
            const f32x4 ft = base[(t & 1) * SPAN + (t >> 1)];   // ds_read_b128
            f32x2 fm; fm.x = ft.x; fm.y = ft.y;
            f32x2 fq; fq.x = ft.z; fq.y = ft.w;
#pragma unroll
            for (int j = 0; j < 2; ++j) {
                const int k = t - j;            // tap index, compile-time
                if (k >= 0 && k < WS) {
                    f32x2 w2; w2.x = g[k]; w2.y = g[k];
                    hm[j] = __builtin_elementwise_fma(w2, fm, hm[j]);
                    hq[j] = __builtin_elementwise_fma(w2, fq, hq[j]);
                }
            }
        }

        float rr[2];
#pragma unroll
        for (int j = 0; j < 2; ++j) {
            const f32x2 m = hm[j];              // {mS, mD}
            const f32x2 q = hq[j];              // {QS, QD}
            const f32x2 msq = m * m;            // {mS^2, mD^2}
            const float t1 = msq.x - msq.y;     // 4*mu1mu2
            const float t2 = msq.x + msq.y;     // 2*(mu1^2+mu2^2)
            const float q1 = q.x - q.y;         // 4*conv(ab)
            const float q2 = q.x + q.y;         // 2*conv(a^2+b^2)
            const float num = fmaf(0.5f, t1, C1c) * fmaf(0.5f, q1 - t1, C2c);
            const float den = fmaf(0.5f, t2, C1c) * fmaf(0.5f, q2 - t2, C2c);
            rr[j] = num * rcp_fast(den);
        }
        f32x2 res; res.x = rr[0]; res.y = rr[1];
        f32x2* po = (f32x2*)&out[pbase + (long)(row0 + ch * R + hr) * Wd + 2 * hu];
        *po = res;

        // ---- V(ch+1) -> hb[(ch+1)&1], overlaps H(ch) in this period ----
        if (ch + 1 < NCH) {
            if (((ch + 1) & 1) == 0) { VPHASE(ch + 1, plaA, plbA, (&hb[0][0])) }
            else                      { VPHASE(ch + 1, plaB, plbB, (&hb[1][0])) }
        }
    }
}

#undef VPHASE
#undef PREFETCH

} // namespace

extern "C" void kernel_launch(void* const* d_in, const int* in_sizes, int n_in,
                              void* d_out, int out_size, void* d_ws, size_t ws_size,
                              hipStream_t stream) {
    const float* img1 = (const float*)d_in[0];
    const float* img2 = (const float*)d_in[1];
    const float* kern = (const float*)d_in[2];
    float* outp = (float*)d_out;
    dim3 grid(Hd / TH, 48);   // 16 bands x 48 planes = 768 blocks, 3/CU resident
    ssim_map_kernel<<<grid, dim3(512), 0, stream>>>(img1, img2, kern, outp);
}

// Round 9
// 152.727 us; speedup vs baseline: 1.0713x; 1.0713x over previous
//
#include <hip/hip_runtime.h>

namespace {

typedef __attribute__((ext_vector_type(2))) float f32x2;
typedef __attribute__((ext_vector_type(4))) float f32x4;

constexpr int Hd = 512, Wd = 512;
constexpr int TH = 32;             // R7 (TH=52): I$ overflow. R2 (TH=16): fill
                                   // overhead. TH=32 is the sweet spot.
constexpr int R  = 4;              // R8 (R=2): LDS reads/col 3.5->6 + 2x barriers
                                   // regressed. Keep 4.
constexpr int NCH = TH / R;        // 8 chunks
constexpr int RAD = 5, WS = 11;
// Transposed staging layout (round-3, kept): staged element e (column e-5) at
// slot s(e) = (e&3)*SPAN + (e>>2). Reads: one base (lane stride 16B, dense) +
// compile-time immediates, conflict-free. Writes: 4 dense 256B segments.
constexpr int SPAN = 131;
constexpr int RSTR = 4 * SPAN;     // 524 f32x4 elements per staged row
constexpr float C1c = 1e-4f;       // (0.01*1.0)^2
constexpr float C2c = 9e-4f;       // (0.03*1.0)^2

__device__ __forceinline__ float rcp_fast(float x) { return __builtin_amdgcn_rcpf(x); }
__device__ __forceinline__ float sgpr_f(float x) {
    return __int_as_float(__builtin_amdgcn_readfirstlane(__float_as_int(x)));
}
__device__ __forceinline__ constexpr int sw(int e) { return (e & 3) * SPAN + (e >> 2); }

// Round-9: R6's overlap schedule with HALF the LDS. R6's double buffer (67KB)
// forced 2 blocks/CU -> 768 blocks ran 1.5 residency rounds (measured
// OccupancyPercent 32%: the tail half-round idles half the machine).
// Only V's LDS WRITES needed the second buffer -- its ring FMAs are
// register-only. So: single 33.5KB buffer; period =
//   {bar1; prefetch(ch+2); H(ch) reads+FMAs+store; V-fma(ch+1) -> est[] regs;
//    bar2; V-write(ch+1) est[] -> LDS}
// Race check: H(ch) reads vs V-write(ch+1): bar2. V-write(ch+1) vs H(ch+1)
// reads: next bar1. bar2's region is ~5 ds_writes (cheap). 33.5KB -> 3
// blocks/CU, 768 = 3x256 EXACTLY: one balanced residency round, 24 waves/CU
// covering barrier drains. est[] adds ~16 VGPR (short live range).

#define VFMA(CH, PA, PB)                                                \
    _Pragma("unroll")                                                   \
    for (int i = 0; i < R; ++i) {                                       \
        const int o = (CH) * R + i;                                     \
        const int j = o + 2 * RAD;                                      \
        const float a = (PA)[i];                                        \
        const float b = (PB)[i];                                        \
        f32x2 sd; sd.x = a + b; sd.y = a - b;                           \
        const f32x2 qq = sd * sd;                                       \
        _Pragma("unroll")                                               \
        for (int k = 0; k < WS; ++k) {                                  \
            const int slot = (j - k) % WS;   /* static after unroll */  \
            f32x2 w2; w2.x = g[k]; w2.y = g[k];                         \
            aM[slot] = __builtin_elementwise_fma(w2, sd, aM[slot]);     \
            aQ[slot] = __builtin_elementwise_fma(w2, qq, aQ[slot]);     \
        }                                                               \
        const int es = o % WS;                                          \
        est[i].x = aM[es].x; est[i].y = aM[es].y;                       \
        est[i].z = aQ[es].x; est[i].w = aQ[es].y;                       \
        aM[es].x = 0.f; aM[es].y = 0.f;                                 \
        aQ[es].x = 0.f; aQ[es].y = 0.f;                                 \
    }

#define VWRITE()                                                        \
    _Pragma("unroll")                                                   \
    for (int i = 0; i < R; ++i) {                                       \
        hb[i * RSTR + wmain] = est[i];                                  \
        if (whalo >= 0) hb[i * RSTR + whalo] = est[i];                  \
    }

#define PREFETCH(CHUNK, PA, PB)                                         \
    _Pragma("unroll")                                                   \
    for (int i = 0; i < R; ++i) {                                       \
        int gr = row0 + RAD + (CHUNK) * R + i;                          \
        gr = (gr >= Hd) ? (2 * Hd - 2 - gr) : gr;                       \
        const long off = pbase + (long)gr * Wd + c;                     \
        (PA)[i] = img1[off];                                            \
        (PB)[i] = img2[off];                                            \
    }

// 33.5 KB LDS -> 3 blocks/CU; (512,6) caps VGPR at 85 (need ~76).
__global__ __launch_bounds__(512, 6) void ssim_map_kernel(
    const float* __restrict__ img1,
    const float* __restrict__ img2,
    const float* __restrict__ kern,
    float* __restrict__ out)
{
    // packed {mS, mD, QS, QD} per column, R rows, transposed slots, ONE buffer
    __shared__ __align__(16) f32x4 hb[R * RSTR];   // 33.5 KB

    const int tid  = threadIdx.x;
    const int c    = tid;                       // owned column
    const int row0 = blockIdx.x * TH;
    const long pbase = (long)blockIdx.y * (long)(Hd * Wd);

    // ---- 1D gaussian (uniform -> SGPRs): g[j] = k[5][j]/sum ----
    float g[WS];
    {
        float s = 0.f;
#pragma unroll
        for (int j = 0; j < WS; ++j) s += kern[RAD * WS + j];
        const float inv = 1.0f / s;
#pragma unroll
        for (int j = 0; j < WS; ++j) g[j] = sgpr_f(kern[RAD * WS + j] * inv);
    }

    // ---- precomputed transposed write slots (loop-invariant) ----
    const int wmain = sw(c + RAD);              // staged element c+5
    int whalo = -1;
    if (c >= 1 && c <= RAD) whalo = sw(RAD - c);                       // left reflect
    else if (c >= Wd - 1 - RAD && c <= Wd - 2) whalo = sw(RAD + 1022 - c); // right

    // ---- ring accumulators, slot(out_row o) = o % 11 ----
    f32x2 aM[WS];   // {conv(S), conv(D)}
    f32x2 aQ[WS];   // {conv(S^2), conv(D^2)}
#pragma unroll
    for (int i = 0; i < WS; ++i) {
        aM[i].x = 0.f; aM[i].y = 0.f;
        aQ[i].x = 0.f; aQ[i].y = 0.f;
    }

    // ---- fill: input idx j=0..9 (rows row0-5+j), taps k<=j ----
#pragma unroll
    for (int j = 0; j < 2 * RAD; ++j) {
        int gr = row0 - RAD + j;                // uniform reflect -> SALU
        gr = (gr < 0) ? -gr : gr;
        gr = (gr >= Hd) ? (2 * Hd - 2 - gr) : gr;
        const long off = pbase + (long)gr * Wd + c;
        const float a = img1[off];
        const float b = img2[off];
        f32x2 sd; sd.x = a + b; sd.y = a - b;
        const f32x2 qq = sd * sd;               // v_pk_mul_f32
#pragma unroll
        for (int k = 0; k < WS; ++k) {
            if (k <= j) {
                const int slot = (j - k) % WS;  // static after unroll
                f32x2 w2; w2.x = g[k]; w2.y = g[k];
                aM[slot] = __builtin_elementwise_fma(w2, sd, aM[slot]);
                aQ[slot] = __builtin_elementwise_fma(w2, qq, aQ[slot]);
            }
        }
    }

    // ---- T14 prefetch registers, double set: V(k) consumes (k even ? A : B)
    float plaA[R], plbA[R], plaB[R], plbB[R];
    PREFETCH(0, plaA, plbA)                     // chunk 0
    PREFETCH(1, plaB, plbB)                     // chunk 1

    // ---- V(0): fma + write (nobody has read hb yet; loop's bar1 fences) ----
    f32x4 est[R];
    VFMA(0, plaA, plbA)
    VWRITE()

    const int hr = tid >> 7;      // horizontal: row in chunk (0..3)
    const int hu = tid & 127;     // horizontal: out cols 4hu..4hu+3

#pragma unroll
    for (int ch = 0; ch < NCH; ++ch) {
        __syncthreads();          // bar1: V-write(ch) visible to H(ch)

        // ---- issue chunk ch+2 loads into the set V(ch) already consumed ----
        if (ch + 2 < NCH) {
            if ((ch & 1) == 0) { PREFETCH(ch + 2, plaA, plbA) }
            else               { PREFETCH(ch + 2, plaB, plbB) }
        }

        // ---- H(ch): 4 cols x 1 row per thread ----
        f32x2 hm[4], hq[4];
#pragma unroll
        for (int j = 0; j < 4; ++j) {
            hm[j].x = 0.f; hm[j].y = 0.f;
            hq[j].x = 0.f; hq[j].y = 0.f;
        }
        // base lane-stride = 1 element (16B): dense wave reads, offsets imm
        const f32x4* base = &hb[hr * RSTR + hu];
#pragma unroll
        for (int t = 0; t < 14; ++t) {          // staged elem 4hu+t (col 4hu+t-5)
            const f32x4 ft = base[(t & 3) * SPAN + (t >> 2)];   // ds_read_b128
            f32x2 fm; fm.x = ft.x; fm.y = ft.y;
            f32x2 fq; fq.x = ft.z; fq.y = ft.w;
#pragma unroll
            for (int j = 0; j < 4; ++j) {
                const int k = t - j;            // tap index, compile-time
                if (k >= 0 && k < WS) {
                    f32x2 w2; w2.x = g[k]; w2.y = g[k];
                    hm[j] = __builtin_elementwise_fma(w2, fm, hm[j]);
                    hq[j] = __builtin_elementwise_fma(w2, fq, hq[j]);
                }
            }
        }

        float rr[4];
#pragma unroll
        for (int j = 0; j < 4; ++j) {
            const f32x2 m = hm[j];              // {mS, mD}
            const f32x2 q = hq[j];              // {QS, QD}
            const f32x2 msq = m * m;            // {mS^2, mD^2}
            const float t1 = msq.x - msq.y;     // 4*mu1mu2
            const float t2 = msq.x + msq.y;     // 2*(mu1^2+mu2^2)
            const float q1 = q.x - q.y;         // 4*conv(ab)
            const float q2 = q.x + q.y;         // 2*conv(a^2+b^2)
            const float num = fmaf(0.5f, t1, C1c) * fmaf(0.5f, q1 - t1, C2c);
            const float den = fmaf(0.5f, t2, C1c) * fmaf(0.5f, q2 - t2, C2c);
            rr[j] = num * rcp_fast(den);
        }
        f32x4 res; res.x = rr[0]; res.y = rr[1]; res.z = rr[2]; res.w = rr[3];
        f32x4* po = (f32x4*)&out[pbase + (long)(row0 + ch * R + hr) * Wd + 4 * hu];
        *po = res;

        // ---- V-fma(ch+1): register-only, overlaps H(ch) in this region ----
        if (ch + 1 < NCH) {
            if (((ch + 1) & 1) == 0) { VFMA(ch + 1, plaA, plbA) }
            else                      { VFMA(ch + 1, plaB, plbB) }

            __syncthreads();      // bar2: H(ch) reads done; safe to overwrite
            VWRITE()              // ~5 ds_writes; next bar1 fences vs H(ch+1)
        }
    }
}

#undef VFMA
#undef VWRITE
#undef PREFETCH

} // namespace

extern "C" void kernel_launch(void* const* d_in, const int* in_sizes, int n_in,
                              void* d_out, int out_size, void* d_ws, size_t ws_size,
                              hipStream_t stream) {
    const float* img1 = (const float*)d_in[0];
    const float* img2 = (const float*)d_in[1];
    const float* kern = (const float*)d_in[2];
    float* outp = (float*)d_out;
    dim3 grid(Hd / TH, 48);   // 16 bands x 48 planes = 768 blocks = 3/CU, balanced
    ssim_map_kernel<<<grid, dim3(512), 0, stream>>>(img1, img2, kern, outp);
}

// Round 10
// 145.026 us; speedup vs baseline: 1.1282x; 1.0531x over previous
//
#include <hip/hip_runtime.h>

namespace {

typedef __attribute__((ext_vector_type(2))) float f32x2;
typedef __attribute__((ext_vector_type(4))) float f32x4;

constexpr int Hd = 512, Wd = 512;
constexpr int TH = 32;             // R7 (TH=52): I$ overflow. R2 (TH=16): fill
                                   // overhead. TH=32 is the sweet spot.
constexpr int R  = 4;              // R8 (R=2): LDS reads/col 3.5->6. Keep 4.
constexpr int NCH = TH / R;        // 8 chunks
constexpr int RAD = 5, WS = 11;
// Transposed staging layout (round-3, kept): staged element e (column e-5) at
// slot s(e) = (e&3)*SPAN + (e>>2). Reads: one base (lane stride 16B, dense) +
// compile-time immediates, conflict-free. Writes: 4 dense 256B segments.
constexpr int SPAN = 131;
constexpr int RSTR = 4 * SPAN;     // 524 f32x4 elements per staged row
constexpr float C1c = 1e-4f;       // (0.01*1.0)^2
constexpr float C2c = 9e-4f;       // (0.03*1.0)^2

__device__ __forceinline__ float rcp_fast(float x) { return __builtin_amdgcn_rcpf(x); }
__device__ __forceinline__ float sgpr_f(float x) {
    return __int_as_float(__builtin_amdgcn_readfirstlane(__float_as_int(x)));
}
__device__ __forceinline__ constexpr int sw(int e) { return (e & 3) * SPAN + (e >> 2); }

// Round-6 schedule (the proven optimum; R9's single-buffer 2-barrier variant
// regressed ~15% despite higher occupancy -- 3rd confirmation that occupancy
// is not the lever; per-block critical path + overlap is): double-buffered
// ping-pong, ONE barrier per chunk. Period = {barrier; prefetch ch+2; H(ch)
// from hb[ch&1]; V(ch+1) into hb[(ch+1)&1]}. V(ch+1)'s writes are separated
// from H(ch-1)'s reads of the same buffer by barrier(ch); in-period H and V
// use different buffers. LDS 67 KB (2 blocks/CU).
// Round-10 addition: T5 s_setprio(1) around the H ds_read+FMA cluster.
// 2 blocks/CU sit at different chunk phases -> at any moment some waves are
// in the latency-critical H cluster, others in register-only V-FMA; priority
// steers issue slots to the waves burning ds_read latency (m191 attn analog).

#define VPHASE(CH, PA, PB, BUF)                                         \
    _Pragma("unroll")                                                   \
    for (int i = 0; i < R; ++i) {                                       \
        const int o = (CH) * R + i;                                     \
        const int j = o + 2 * RAD;                                      \
        const float a = (PA)[i];                                        \
        const float b = (PB)[i];                                        \
        f32x2 sd; sd.x = a + b; sd.y = a - b;                           \
        const f32x2 qq = sd * sd;                                       \
        _Pragma("unroll")                                               \
        for (int k = 0; k < WS; ++k) {                                  \
            const int slot = (j - k) % WS;   /* static after unroll */  \
            f32x2 w2; w2.x = g[k]; w2.y = g[k];                         \
            aM[slot] = __builtin_elementwise_fma(w2, sd, aM[slot]);     \
            aQ[slot] = __builtin_elementwise_fma(w2, qq, aQ[slot]);     \
        }                                                               \
        const int es = o % WS;                                          \
        f32x4 e;                                                        \
        e.x = aM[es].x; e.y = aM[es].y;                                 \
        e.z = aQ[es].x; e.w = aQ[es].y;                                 \
        (BUF)[i * RSTR + wmain] = e;                                    \
        if (whalo >= 0) (BUF)[i * RSTR + whalo] = e;                    \
        aM[es].x = 0.f; aM[es].y = 0.f;                                 \
        aQ[es].x = 0.f; aQ[es].y = 0.f;                                 \
    }

#define PREFETCH(CHUNK, PA, PB)                                         \
    _Pragma("unroll")                                                   \
    for (int i = 0; i < R; ++i) {                                       \
        int gr = row0 + RAD + (CHUNK) * R + i;                          \
        gr = (gr >= Hd) ? (2 * Hd - 2 - gr) : gr;                       \
        const long off = pbase + (long)gr * Wd + c;                     \
        (PA)[i] = img1[off];                                            \
        (PB)[i] = img2[off];                                            \
    }

__global__ __launch_bounds__(512, 4) void ssim_map_kernel(
    const float* __restrict__ img1,
    const float* __restrict__ img2,
    const float* __restrict__ kern,
    float* __restrict__ out)
{
    // packed {mS, mD, QS, QD} per column, R rows, transposed slots, x2 buffers
    __shared__ __align__(16) f32x4 hb[2][R * RSTR];   // 67 KB

    const int tid  = threadIdx.x;
    const int c    = tid;                       // owned column
    const int row0 = blockIdx.x * TH;
    const long pbase = (long)blockIdx.y * (long)(Hd * Wd);

    // ---- 1D gaussian (uniform -> SGPRs): g[j] = k[5][j]/sum ----
    float g[WS];
    {
        float s = 0.f;
#pragma unroll
        for (int j = 0; j < WS; ++j) s += kern[RAD * WS + j];
        const float inv = 1.0f / s;
#pragma unroll
        for (int j = 0; j < WS; ++j) g[j] = sgpr_f(kern[RAD * WS + j] * inv);
    }

    // ---- precomputed transposed write slots (loop-invariant) ----
    const int wmain = sw(c + RAD);              // staged element c+5
    int whalo = -1;
    if (c >= 1 && c <= RAD) whalo = sw(RAD - c);                       // left reflect
    else if (c >= Wd - 1 - RAD && c <= Wd - 2) whalo = sw(RAD + 1022 - c); // right

    // ---- ring accumulators, slot(out_row o) = o % 11 ----
    f32x2 aM[WS];   // {conv(S), conv(D)}
    f32x2 aQ[WS];   // {conv(S^2), conv(D^2)}
#pragma unroll
    for (int i = 0; i < WS; ++i) {
        aM[i].x = 0.f; aM[i].y = 0.f;
        aQ[i].x = 0.f; aQ[i].y = 0.f;
    }

    // ---- fill: input idx j=0..9 (rows row0-5+j), taps k<=j ----
#pragma unroll
    for (int j = 0; j < 2 * RAD; ++j) {
        int gr = row0 - RAD + j;                // uniform reflect -> SALU
        gr = (gr < 0) ? -gr : gr;
        gr = (gr >= Hd) ? (2 * Hd - 2 - gr) : gr;
        const long off = pbase + (long)gr * Wd + c;
        const float a = img1[off];
        const float b = img2[off];
        f32x2 sd; sd.x = a + b; sd.y = a - b;
        const f32x2 qq = sd * sd;               // v_pk_mul_f32
#pragma unroll
        for (int k = 0; k < WS; ++k) {
            if (k <= j) {
                const int slot = (j - k) % WS;  // static after unroll
                f32x2 w2; w2.x = g[k]; w2.y = g[k];
                aM[slot] = __builtin_elementwise_fma(w2, sd, aM[slot]);
                aQ[slot] = __builtin_elementwise_fma(w2, qq, aQ[slot]);
            }
        }
    }

    // ---- T14 prefetch registers, double set: V(k) consumes (k even ? A : B)
    float plaA[R], plbA[R], plaB[R], plbB[R];
    PREFETCH(0, plaA, plbA)                     // chunk 0
    PREFETCH(1, plaB, plbB)                     // chunk 1

    // ---- V(0) -> hb[0] (no barrier needed before first use) ----
    VPHASE(0, plaA, plbA, (&hb[0][0]))

    const int hr = tid >> 7;      // horizontal: row in chunk (0..3)
    const int hu = tid & 127;     // horizontal: out cols 4hu..4hu+3

#pragma unroll
    for (int ch = 0; ch < NCH; ++ch) {
        __syncthreads();          // hb[ch&1] complete; prior readers of
                                  // hb[(ch+1)&1] (H(ch-1)) are done

        // ---- issue chunk ch+2 loads into the set V(ch) already consumed ----
        if (ch + 2 < NCH) {
            if ((ch & 1) == 0) { PREFETCH(ch + 2, plaA, plbA) }
            else               { PREFETCH(ch + 2, plaB, plbB) }
        }

        // ---- H(ch): 4 cols x 1 row per thread, reads hb[ch&1] ----
        f32x2 hm[4], hq[4];
#pragma unroll
        for (int j = 0; j < 4; ++j) {
            hm[j].x = 0.f; hm[j].y = 0.f;
            hq[j].x = 0.f; hq[j].y = 0.f;
        }
        // base lane-stride = 1 element (16B): dense wave reads, offsets imm
        const f32x4* base = &hb[ch & 1][hr * RSTR + hu];
        __builtin_amdgcn_s_setprio(1);          // latency-critical LDS cluster
#pragma unroll
        for (int t = 0; t < 14; ++t) {          // staged elem 4hu+t (col 4hu+t-5)
            const f32x4 ft = base[(t & 3) * SPAN + (t >> 2)];   // ds_read_b128
            f32x2 fm; fm.x = ft.x; fm.y = ft.y;
            f32x2 fq; fq.x = ft.z; fq.y = ft.w;
#pragma unroll
            for (int j = 0; j < 4; ++j) {
                const int k = t - j;            // tap index, compile-time
                if (k >= 0 && k < WS) {
                    f32x2 w2; w2.x = g[k]; w2.y = g[k];
                    hm[j] = __builtin_elementwise_fma(w2, fm, hm[j]);
                    hq[j] = __builtin_elementwise_fma(w2, fq, hq[j]);
                }
            }
        }
        __builtin_amdgcn_s_setprio(0);          // V-FMA runs at default prio

        float rr[4];
#pragma unroll
        for (int j = 0; j < 4; ++j) {
            const f32x2 m = hm[j];              // {mS, mD}
            const f32x2 q = hq[j];              // {QS, QD}
            const f32x2 msq = m * m;            // {mS^2, mD^2}
            const float t1 = msq.x - msq.y;     // 4*mu1mu2
            const float t2 = msq.x + msq.y;     // 2*(mu1^2+mu2^2)
            const float q1 = q.x - q.y;         // 4*conv(ab)
            const float q2 = q.x + q.y;         // 2*conv(a^2+b^2)
            const float num = fmaf(0.5f, t1, C1c) * fmaf(0.5f, q1 - t1, C2c);
            const float den = fmaf(0.5f, t2, C1c) * fmaf(0.5f, q2 - t2, C2c);
            rr[j] = num * rcp_fast(den);
        }
        f32x4 res; res.x = rr[0]; res.y = rr[1]; res.z = rr[2]; res.w = rr[3];
        f32x4* po = (f32x4*)&out[pbase + (long)(row0 + ch * R + hr) * Wd + 4 * hu];
        *po = res;

        // ---- V(ch+1) -> hb[(ch+1)&1], overlaps H(ch) in this period ----
        if (ch + 1 < NCH) {
            if (((ch + 1) & 1) == 0) { VPHASE(ch + 1, plaA, plbA, (&hb[0][0])) }
            else                      { VPHASE(ch + 1, plaB, plbB, (&hb[1][0])) }
        }
    }
}

#undef VPHASE
#undef PREFETCH

} // namespace

extern "C" void kernel_launch(void* const* d_in, const int* in_sizes, int n_in,
                              void* d_out, int out_size, void* d_ws, size_t ws_size,
                              hipStream_t stream) {
    const float* img1 = (const float*)d_in[0];
    const float* img2 = (const float*)d_in[1];
    const float* kern = (const float*)d_in[2];
    float* outp = (float*)d_out;
    dim3 grid(Hd / TH, 48);   // 16 bands x 48 planes = 768 blocks
    ssim_map_kernel<<<grid, dim3(512), 0, stream>>>(img1, img2, kern, outp);
}